// Round 1
// baseline (450.500 us; speedup 1.0000x reference)
//
#include <hip/hip_runtime.h>
#include <math.h>

#define BATCH 64
#define LSEQ  16384
#define DIM   64
#define KSEL  256
#define KPAD  384   // fp32-surrogate select rank (128-rank safety slack over KSEL)
#define NCAND 512   // candidate cap (compaction + bitonic width)

// ---------------------------------------------------------------------------
// Single fused kernel, ONE BLOCK PER BATCH, 1024 threads, NO WORKSPACE.
// Phase 1: fp32 surrogate s = dot*|dot|/kss (monotone in cosine sim per batch,
//          |q| and g drop out) -> sortable u32 keys in LDS (64 KB), with a
//          fused 8-way-replicated top-byte histogram (low atomic contention).
// Phase 2: 2-pass radix on the 16-bit key prefix -> threshold at rank KPAD,
//          compact <=512 candidate row indices. fp32 noise (~2e-5) vs
//          rank-256 spacing (~7e-3) makes the 128-rank slack bulletproof.
// Phase 3: exact fp64 sims for candidates only, using the bit-identical
//          formula + reduction tree of the previously-verified kernel, then
//          the verified bitonic-512 sort + fp64 softmax epilogue.
// ---------------------------------------------------------------------------

__device__ __forceinline__ void reduce_hist(unsigned (*histR)[256],
                                            unsigned* hist, int t)
{
    if (t < 256) {
        unsigned h = 0;
        #pragma unroll
        for (int r = 0; r < 8; ++r) h += histR[r][t];
        hist[t] = h;
    }
    __syncthreads();
}

// inclusive suffix sum over 256 bins: scan[t] = sum_{e>=t} hist[e]
__device__ __forceinline__ void suffix_scan_256(const unsigned* hist,
                                                unsigned* scan,
                                                unsigned* wbase, int t)
{
    const int lane = t & 63, w4 = t >> 6;
    unsigned v = (t < 256) ? hist[t] : 0u;
    #pragma unroll
    for (int off = 1; off < 64; off <<= 1) {
        unsigned u2 = __shfl_down(v, off);
        if (lane + off < 64) v += u2;   // guard with OWN lane; OOB shfl unused
    }
    if (t < 256 && lane == 0) wbase[w4] = v;   // per-wave total
    __syncthreads();
    if (t < 256) {
        for (int w = w4 + 1; w < 4; ++w) v += wbase[w];
        scan[t] = v;
    }
    __syncthreads();
}

__global__ __launch_bounds__(1024) void fused_topk_kernel(
    const float* __restrict__ q,
    const float* __restrict__ keys,
    const float* __restrict__ values,
    const float* __restrict__ gp,
    float* __restrict__ out)
{
    const int b = blockIdx.x;
    const int t = threadIdx.x;

    __shared__ unsigned   skey[LSEQ];       // 64 KB sortable fp32 surrogate keys
    __shared__ unsigned   histR[8][256];    // 8 KB replicated histogram
    __shared__ unsigned   hist[256];
    __shared__ unsigned   scan[256];
    __shared__ unsigned   wbase[4];
    __shared__ unsigned   cidx[NCAND];      // candidate row indices
    __shared__ ulonglong2 cand[NCAND];      // {sortable fp64 key, ~idx}
    __shared__ double     wsum[4];
    __shared__ unsigned   sh_hi8, sh_k, sh_t16, ccount;

    // ---- init ----
    ((unsigned*)histR)[t]        = 0u;
    ((unsigned*)histR)[t + 1024] = 0u;
    if (t == 0) { ccount = 0u; sh_hi8 = 0u; sh_k = KPAD; sh_t16 = 0u; }
    __syncthreads();

    // ---- Phase 1: fp32 surrogate sims, 4 lanes per key row ----
    const int lane4 = t & 3;                 // float4-quad within row
    const int rbase = t >> 2;                // 0..255: row within sweep
    const float4* k4 = reinterpret_cast<const float4*>(keys)
                     + (size_t)b * LSEQ * (DIM / 4);
    const float4* q4 = reinterpret_cast<const float4*>(q) + b * (DIM / 4);

    float4 qa = q4[lane4 * 4 + 0];
    float4 qb = q4[lane4 * 4 + 1];
    float4 qc = q4[lane4 * 4 + 2];
    float4 qd = q4[lane4 * 4 + 3];
    const int rep = (t >> 2) & 7;            // spread atomics over 8 replicas

    #pragma unroll 2
    for (int it = 0; it < 64; ++it) {
        const int row = it * 256 + rbase;
        const float4* kp = k4 + row * 16 + lane4 * 4;
        float4 ka = kp[0], kb = kp[1], kc = kp[2], kd = kp[3];

        float dot = qa.x*ka.x + qa.y*ka.y + qa.z*ka.z + qa.w*ka.w
                  + qb.x*kb.x + qb.y*kb.y + qb.z*kb.z + qb.w*kb.w
                  + qc.x*kc.x + qc.y*kc.y + qc.z*kc.z + qc.w*kc.w
                  + qd.x*kd.x + qd.y*kd.y + qd.z*kd.z + qd.w*kd.w;
        float kss = ka.x*ka.x + ka.y*ka.y + ka.z*ka.z + ka.w*ka.w
                  + kb.x*kb.x + kb.y*kb.y + kb.z*kb.z + kb.w*kb.w
                  + kc.x*kc.x + kc.y*kc.y + kc.z*kc.z + kc.w*kc.w
                  + kd.x*kd.x + kd.y*kd.y + kd.z*kd.z + kd.w*kd.w;
        dot += __shfl_xor(dot, 1); dot += __shfl_xor(dot, 2);
        kss += __shfl_xor(kss, 1); kss += __shfl_xor(kss, 2);

        if (lane4 == 0) {
            float s = dot * fabsf(dot) / kss;          // monotone surrogate
            unsigned u = __float_as_uint(s);
            unsigned key = (u >> 31) ? ~u : (u | 0x80000000u);
            skey[row] = key;
            atomicAdd(&histR[rep][key >> 24], 1u);     // fused pass-0 hist
        }
    }
    __syncthreads();

    // ---- Phase 2a: radix pass 0 (top 8 bits) ----
    reduce_hist(histR, hist, t);
    suffix_scan_256(hist, scan, wbase, t);
    if (t < 256 && scan[t] >= KPAD && (t == 255 || scan[t + 1] < KPAD)) {
        sh_hi8 = (unsigned)t;
        sh_k   = KPAD - ((t == 255) ? 0u : scan[t + 1]);
    }
    __syncthreads();

    // ---- Phase 2b: radix pass 1 (next 8 bits, within chosen bin) ----
    ((unsigned*)histR)[t]        = 0u;
    ((unsigned*)histR)[t + 1024] = 0u;
    __syncthreads();
    const unsigned hi8  = sh_hi8;
    const unsigned kcur = sh_k;
    #pragma unroll
    for (int it = 0; it < 16; ++it) {
        unsigned key = skey[it * 1024 + t];
        if ((key >> 24) == hi8)
            atomicAdd(&histR[t & 7][(key >> 16) & 255u], 1u);
    }
    __syncthreads();
    reduce_hist(histR, hist, t);
    suffix_scan_256(hist, scan, wbase, t);
    if (t < 256 && scan[t] >= kcur && (t == 255 || scan[t + 1] < kcur))
        sh_t16 = (hi8 << 8) | (unsigned)t;
    __syncthreads();
    const unsigned T16 = sh_t16;

    // ---- Phase 2c: compact candidates (key16 >= T16): count in [384, ~450] ----
    #pragma unroll
    for (int it = 0; it < 16; ++it) {
        const int l = it * 1024 + t;
        unsigned key = skey[l];
        if ((key >> 16) >= T16) {
            unsigned pos = atomicAdd(&ccount, 1u);
            if (pos < NCAND) cidx[pos] = (unsigned)l;
        }
    }
    __syncthreads();
    const unsigned total = (ccount < (unsigned)NCAND) ? ccount : (unsigned)NCAND;

    // ---- Phase 3: exact fp64 sims for candidates (verified numerics) ----
    const int j = t & 15;                    // original 16-lane layout
    const float4 qv = q4[j];
    const double qx = qv.x, qy = qv.y, qz = qv.z, qw = qv.w;
    double qss = qx*qx + qy*qy + qz*qz + qw*qw;
    #pragma unroll
    for (int m = 1; m < 16; m <<= 1) qss += __shfl_xor(qss, m);
    const double scale = (double)gp[0] / sqrt(qss);

    const int cslot = t >> 4;                // 0..63 candidates per sweep
    for (int sweep = 0; sweep < NCAND / 64; ++sweep) {
        const int cc = sweep * 64 + cslot;
        if (cc < (int)total) {
            const int row = (int)cidx[cc];
            float4 kv = k4[row * 16 + j];
            const double kx = kv.x, ky = kv.y, kz = kv.z, kw = kv.w;
            double dot = qx*kx + qy*ky + qz*kz + qw*kw;
            double kss = kx*kx + ky*ky + kz*kz + kw*kw;
            #pragma unroll
            for (int m = 1; m < 16; m <<= 1) {
                dot += __shfl_xor(dot, m);
                kss += __shfl_xor(kss, m);
            }
            if (j == 0) {
                double sim = scale * dot / sqrt(kss);
                unsigned long long u =
                    (unsigned long long)__double_as_longlong(sim);
                unsigned long long k64 =
                    (u >> 63) ? ~u : (u | 0x8000000000000000ull);
                cand[cc] = make_ulonglong2(
                    k64, (unsigned long long)(0xFFFFFFFFu - (unsigned)row));
            }
        } else if (j == 0) {
            cand[cc] = make_ulonglong2(0ull, 0ull);   // pad = smallest
        }
    }
    __syncthreads();

    // ---- bitonic sort 512 ascending by (key, ~idx) (verified network) ----
    for (int size = 2; size <= NCAND; size <<= 1) {
        for (int stride = size >> 1; stride > 0; stride >>= 1) {
            __syncthreads();
            if (t < 256) {
                int i  = ((t & ~(stride - 1)) << 1) | (t & (stride - 1));
                int jj = i + stride;
                bool up = ((i & size) == 0);
                ulonglong2 a = cand[i], c = cand[jj];
                bool agt = (a.x > c.x) || (a.x == c.x && a.y > c.y);
                if (agt == up) { cand[i] = c; cand[jj] = a; }
            }
        }
    }
    __syncthreads();

    // ---- epilogue: softmax (fp64, verified) + values gather ----
    double e = 0.0;
    unsigned idx = 0u;
    if (t < 256) {
        ulonglong2 v = cand[511 - t];
        idx = 0xFFFFFFFFu - (unsigned)v.y;
        unsigned long long ub = (v.x & 0x8000000000000000ull)
                              ? (v.x ^ 0x8000000000000000ull) : ~v.x;
        double sv = __longlong_as_double((long long)ub);

        ulonglong2 vm = cand[511];
        unsigned long long um = (vm.x & 0x8000000000000000ull)
                              ? (vm.x ^ 0x8000000000000000ull) : ~vm.x;
        double fm = __longlong_as_double((long long)um);

        e = exp(sv - fm);
        double esum = e;
        #pragma unroll
        for (int m = 1; m < 64; m <<= 1) esum += __shfl_xor(esum, m);
        if ((t & 63) == 0) wsum[t >> 6] = esum;
    }
    __syncthreads();
    if (t < 256) {
        const double tot = wsum[0] + wsum[1] + wsum[2] + wsum[3];
        out[b * KSEL + t]                = values[(size_t)b * LSEQ + idx];
        out[BATCH * KSEL + b * KSEL + t] = (float)(e / tot);
    }
}

// ---------------------------------------------------------------------------
extern "C" void kernel_launch(void* const* d_in, const int* in_sizes, int n_in,
                              void* d_out, int out_size, void* d_ws, size_t ws_size,
                              hipStream_t stream)
{
    (void)d_ws; (void)ws_size;   // deliberately workspace-free (poison-fill test)
    const float* q      = (const float*)d_in[0];  // (B,1,D)
    const float* keys   = (const float*)d_in[1];  // (B,L,D)
    const float* values = (const float*)d_in[2];  // (B,L,1)
    const float* g      = (const float*)d_in[3];  // scalar
    float* out = (float*)d_out;                   // [B*K values_sel | B*K weights]

    fused_topk_kernel<<<dim3(BATCH), dim3(1024), 0, stream>>>(q, keys, values, g, out);
}

// Round 2
// 392.243 us; speedup vs baseline: 1.1485x; 1.1485x over previous
//
#include <hip/hip_runtime.h>
#include <math.h>

#define BATCH 64
#define LSEQ  16384
#define DIM   64
#define KSEL  256
#define KPAD  384   // fp32-surrogate select rank (128-rank safety slack over KSEL)
#define NCAND 512   // candidate cap (compaction + bitonic width)

// ---------------------------------------------------------------------------
// Two-kernel pipeline. The harness poisons the 1 GB workspace regardless of
// use (round-1 finding), so ws is free: use it for 4 MB of fp32 surrogate keys.
//
// K1 (4096 blocks, full chip): fp32 surrogate s = dot*|dot|/kss (monotone in
//     cosine sim per batch; |q| and g drop out) -> sortable u32 keys in ws.
//     Round-0 verified 16-lane layout: wave = 4 rows x 1 KB contiguous loads.
// K2 (64 blocks x 1024): per-batch select, all LDS-resident. Verified round-1
//     phases: replicated-histogram radix to rank KPAD on 16-bit prefix ->
//     compact <=512 candidates -> exact fp64 sims (bit-identical formula +
//     reduction tree of the verified kernel) -> bitonic-512 -> fp64 softmax.
//     fp32 noise (~2e-5) vs rank-256 spacing (~7e-3): 128-rank slack is safe.
// ---------------------------------------------------------------------------

__global__ __launch_bounds__(256) void sim32_kernel(
    const float* __restrict__ q,
    const float* __restrict__ keys,
    unsigned* __restrict__ skeys)
{
    const int b     = blockIdx.x >> 6;   // 64 chunks per batch
    const int chunk = blockIdx.x & 63;   // 256 rows per chunk
    const int t  = threadIdx.x;
    const int j  = t & 15;               // float4 slot within row
    const int rl = t >> 4;               // row within 16-row group

    const float4* q4 = reinterpret_cast<const float4*>(q) + b * 16;
    float4 qv = q4[j];
    const float qx = qv.x, qy = qv.y, qz = qv.z, qw = qv.w;

    const float4* k4 = reinterpret_cast<const float4*>(keys) + (size_t)b * LSEQ * 16;
    const int row_base = chunk * 256;
    unsigned* sk = skeys + (size_t)b * LSEQ;

    for (int it = 0; it < 16; ++it) {
        const int row = row_base + it * 16 + rl;
        float4 kv = k4[row * 16 + j];
        float dot = qx*kv.x + qy*kv.y + qz*kv.z + qw*kv.w;
        float kss = kv.x*kv.x + kv.y*kv.y + kv.z*kv.z + kv.w*kv.w;
        #pragma unroll
        for (int m = 1; m < 16; m <<= 1) {
            dot += __shfl_xor(dot, m);
            kss += __shfl_xor(kss, m);
        }
        if (j == 0) {
            float s = dot * fabsf(dot) / kss;        // monotone surrogate
            unsigned u = __float_as_uint(s);
            sk[row] = (u >> 31) ? ~u : (u | 0x80000000u);
        }
    }
}

__device__ __forceinline__ void reduce_hist(unsigned (*histR)[256],
                                            unsigned* hist, int t)
{
    if (t < 256) {
        unsigned h = 0;
        #pragma unroll
        for (int r = 0; r < 8; ++r) h += histR[r][t];
        hist[t] = h;
    }
    __syncthreads();
}

// inclusive suffix sum over 256 bins: scan[t] = sum_{e>=t} hist[e]
__device__ __forceinline__ void suffix_scan_256(const unsigned* hist,
                                                unsigned* scan,
                                                unsigned* wbase, int t)
{
    const int lane = t & 63, w4 = t >> 6;
    unsigned v = (t < 256) ? hist[t] : 0u;
    #pragma unroll
    for (int off = 1; off < 64; off <<= 1) {
        unsigned u2 = __shfl_down(v, off);
        if (lane + off < 64) v += u2;
    }
    if (t < 256 && lane == 0) wbase[w4] = v;
    __syncthreads();
    if (t < 256) {
        for (int w = w4 + 1; w < 4; ++w) v += wbase[w];
        scan[t] = v;
    }
    __syncthreads();
}

__global__ __launch_bounds__(1024) void topk_kernel(
    const float* __restrict__ q,
    const float* __restrict__ keys,
    const float* __restrict__ values,
    const float* __restrict__ gp,
    const unsigned* __restrict__ skeys,
    float* __restrict__ out)
{
    const int b = blockIdx.x;
    const int t = threadIdx.x;

    __shared__ unsigned   skey[LSEQ];       // 64 KB surrogate keys
    __shared__ unsigned   histR[8][256];    // 8 KB replicated histogram
    __shared__ unsigned   hist[256];
    __shared__ unsigned   scan[256];
    __shared__ unsigned   wbase[4];
    __shared__ unsigned   cidx[NCAND];      // candidate row indices
    __shared__ ulonglong2 cand[NCAND];      // {sortable fp64 key, ~idx}
    __shared__ double     wsum[4];
    __shared__ unsigned   sh_hi8, sh_k, sh_t16, ccount;

    // ---- init ----
    ((unsigned*)histR)[t]        = 0u;
    ((unsigned*)histR)[t + 1024] = 0u;
    if (t == 0) { ccount = 0u; sh_hi8 = 0u; sh_k = KPAD; sh_t16 = 0u; }
    __syncthreads();

    // ---- load keys ws -> LDS (uint4), fused pass-0 histogram ----
    const uint4* wk4 = reinterpret_cast<const uint4*>(skeys + (size_t)b * LSEQ);
    #pragma unroll
    for (int it = 0; it < 4; ++it) {
        const int i = it * 1024 + t;
        uint4 v = wk4[i];
        reinterpret_cast<uint4*>(skey)[i] = v;
        atomicAdd(&histR[t & 7][v.x >> 24], 1u);
        atomicAdd(&histR[t & 7][v.y >> 24], 1u);
        atomicAdd(&histR[t & 7][v.z >> 24], 1u);
        atomicAdd(&histR[t & 7][v.w >> 24], 1u);
    }
    __syncthreads();

    // ---- radix pass 0 (top 8 bits) ----
    reduce_hist(histR, hist, t);
    suffix_scan_256(hist, scan, wbase, t);
    if (t < 256 && scan[t] >= KPAD && (t == 255 || scan[t + 1] < KPAD)) {
        sh_hi8 = (unsigned)t;
        sh_k   = KPAD - ((t == 255) ? 0u : scan[t + 1]);
    }
    __syncthreads();

    // ---- radix pass 1 (next 8 bits, within chosen bin) ----
    ((unsigned*)histR)[t]        = 0u;
    ((unsigned*)histR)[t + 1024] = 0u;
    __syncthreads();
    const unsigned hi8  = sh_hi8;
    const unsigned kcur = sh_k;
    #pragma unroll
    for (int it = 0; it < 16; ++it) {
        unsigned key = skey[it * 1024 + t];
        if ((key >> 24) == hi8)
            atomicAdd(&histR[t & 7][(key >> 16) & 255u], 1u);
    }
    __syncthreads();
    reduce_hist(histR, hist, t);
    suffix_scan_256(hist, scan, wbase, t);
    if (t < 256 && scan[t] >= kcur && (t == 255 || scan[t + 1] < kcur))
        sh_t16 = (hi8 << 8) | (unsigned)t;
    __syncthreads();
    const unsigned T16 = sh_t16;

    // ---- compact candidates (key16 >= T16) ----
    #pragma unroll
    for (int it = 0; it < 16; ++it) {
        const int l = it * 1024 + t;
        unsigned key = skey[l];
        if ((key >> 16) >= T16) {
            unsigned pos = atomicAdd(&ccount, 1u);
            if (pos < NCAND) cidx[pos] = (unsigned)l;
        }
    }
    __syncthreads();
    const unsigned total = (ccount < (unsigned)NCAND) ? ccount : (unsigned)NCAND;

    // ---- exact fp64 sims for candidates (verified numerics) ----
    const float4* q4 = reinterpret_cast<const float4*>(q) + b * (DIM / 4);
    const float4* k4 = reinterpret_cast<const float4*>(keys)
                     + (size_t)b * LSEQ * (DIM / 4);
    const int j = t & 15;
    const float4 qv = q4[j];
    const double qx = qv.x, qy = qv.y, qz = qv.z, qw = qv.w;
    double qss = qx*qx + qy*qy + qz*qz + qw*qw;
    #pragma unroll
    for (int m = 1; m < 16; m <<= 1) qss += __shfl_xor(qss, m);
    const double scale = (double)gp[0] / sqrt(qss);

    const int cslot = t >> 4;                // 64 candidates per sweep
    for (int sweep = 0; sweep < NCAND / 64; ++sweep) {
        const int cc = sweep * 64 + cslot;
        if (cc < (int)total) {
            const int row = (int)cidx[cc];
            float4 kv = k4[row * 16 + j];
            const double kx = kv.x, ky = kv.y, kz = kv.z, kw = kv.w;
            double dot = qx*kx + qy*ky + qz*kz + qw*kw;
            double kss = kx*kx + ky*ky + kz*kz + kw*kw;
            #pragma unroll
            for (int m = 1; m < 16; m <<= 1) {
                dot += __shfl_xor(dot, m);
                kss += __shfl_xor(kss, m);
            }
            if (j == 0) {
                double sim = scale * dot / sqrt(kss);
                unsigned long long u =
                    (unsigned long long)__double_as_longlong(sim);
                unsigned long long k64 =
                    (u >> 63) ? ~u : (u | 0x8000000000000000ull);
                cand[cc] = make_ulonglong2(
                    k64, (unsigned long long)(0xFFFFFFFFu - (unsigned)row));
            }
        } else if (j == 0) {
            cand[cc] = make_ulonglong2(0ull, 0ull);   // pad = smallest
        }
    }
    __syncthreads();

    // ---- bitonic sort 512 ascending by (key, ~idx) (verified network) ----
    for (int size = 2; size <= NCAND; size <<= 1) {
        for (int stride = size >> 1; stride > 0; stride >>= 1) {
            __syncthreads();
            if (t < 256) {
                int i  = ((t & ~(stride - 1)) << 1) | (t & (stride - 1));
                int jj = i + stride;
                bool up = ((i & size) == 0);
                ulonglong2 a = cand[i], c = cand[jj];
                bool agt = (a.x > c.x) || (a.x == c.x && a.y > c.y);
                if (agt == up) { cand[i] = c; cand[jj] = a; }
            }
        }
    }
    __syncthreads();

    // ---- epilogue: softmax (fp64, verified) + values gather ----
    double e = 0.0;
    unsigned idx = 0u;
    if (t < 256) {
        ulonglong2 v = cand[511 - t];
        idx = 0xFFFFFFFFu - (unsigned)v.y;
        unsigned long long ub = (v.x & 0x8000000000000000ull)
                              ? (v.x ^ 0x8000000000000000ull) : ~v.x;
        double sv = __longlong_as_double((long long)ub);

        ulonglong2 vm = cand[511];
        unsigned long long um = (vm.x & 0x8000000000000000ull)
                              ? (vm.x ^ 0x8000000000000000ull) : ~vm.x;
        double fm = __longlong_as_double((long long)um);

        e = exp(sv - fm);
        double esum = e;
        #pragma unroll
        for (int m = 1; m < 64; m <<= 1) esum += __shfl_xor(esum, m);
        if ((t & 63) == 0) wsum[t >> 6] = esum;
    }
    __syncthreads();
    if (t < 256) {
        const double tot = wsum[0] + wsum[1] + wsum[2] + wsum[3];
        out[b * KSEL + t]                = values[(size_t)b * LSEQ + idx];
        out[BATCH * KSEL + b * KSEL + t] = (float)(e / tot);
    }
}

// ---------------------------------------------------------------------------
extern "C" void kernel_launch(void* const* d_in, const int* in_sizes, int n_in,
                              void* d_out, int out_size, void* d_ws, size_t ws_size,
                              hipStream_t stream)
{
    const float* q      = (const float*)d_in[0];  // (B,1,D)
    const float* keys   = (const float*)d_in[1];  // (B,L,D)
    const float* values = (const float*)d_in[2];  // (B,L,1)
    const float* g      = (const float*)d_in[3];  // scalar
    float* out  = (float*)d_out;                  // [B*K values_sel | B*K weights]
    unsigned* skeys = (unsigned*)d_ws;            // 4 MB surrogate keys

    sim32_kernel<<<dim3(BATCH * (LSEQ / 256)), dim3(256), 0, stream>>>(q, keys, skeys);
    topk_kernel<<<dim3(BATCH), dim3(1024), 0, stream>>>(q, keys, values, g, skeys, out);
}

// Round 3
// 390.700 us; speedup vs baseline: 1.1531x; 1.0039x over previous
//
#include <hip/hip_runtime.h>
#include <math.h>

#define BATCH 64
#define LSEQ  16384
#define DIM   64
#define KSEL  256
#define KPAD  384   // fp32-surrogate select rank (128-rank safety slack over KSEL)
#define NCAND 512   // candidate cap (compaction + bitonic width)

// ---------------------------------------------------------------------------
// Two-kernel pipeline. Harness poisons the 1 GB workspace regardless of use
// (~2x160 us fixed tax), so ws is free: 4 MB of fp32 surrogate keys.
//
// K1 (4096 blocks, full chip, BW-bound): fp32 surrogate s = dot*|dot|/kss
//     (monotone in cosine sim per batch; |q| and g drop out) -> sortable u32.
//     4 lanes/row x 16 floats/lane (round-1-verified pattern): only 2 shuffle
//     steps per reduction (vs 5 for 16-lane), 64 B contiguous stores/wave.
// K2 (64 blocks x 1024, byte-identical to round-2 verified): replicated-
//     histogram radix to rank KPAD on 16-bit prefix -> compact <=512
//     candidates -> exact fp64 sims (bit-identical formula + reduction tree)
//     -> bitonic-512 -> fp64 softmax. fp32 noise (~2e-5) vs rank-256 spacing
//     (~7e-3): 128-rank slack is safe.
// ---------------------------------------------------------------------------

__global__ __launch_bounds__(256) void sim32_kernel(
    const float* __restrict__ q,
    const float* __restrict__ keys,
    unsigned* __restrict__ skeys)
{
    const int b     = blockIdx.x >> 6;   // 64 chunks per batch
    const int chunk = blockIdx.x & 63;   // 256 rows per chunk
    const int t     = threadIdx.x;
    const int lane4 = t & 3;             // float4-quad group within row
    const int r     = t >> 2;            // 0..63: row within sweep

    const float4* q4 = reinterpret_cast<const float4*>(q) + b * 16;
    const float4 qa = q4[lane4 * 4 + 0];
    const float4 qb = q4[lane4 * 4 + 1];
    const float4 qc = q4[lane4 * 4 + 2];
    const float4 qd = q4[lane4 * 4 + 3];

    const float4* k4 = reinterpret_cast<const float4*>(keys) + (size_t)b * LSEQ * 16;
    unsigned* sk = skeys + (size_t)b * LSEQ;
    const int row_base = chunk * 256;

    #pragma unroll
    for (int it = 0; it < 4; ++it) {
        const int row = row_base + it * 64 + r;
        const float4* kp = k4 + row * 16 + lane4 * 4;
        const float4 ka = kp[0], kb = kp[1], kc = kp[2], kd = kp[3];

        float dot = qa.x*ka.x + qa.y*ka.y + qa.z*ka.z + qa.w*ka.w
                  + qb.x*kb.x + qb.y*kb.y + qb.z*kb.z + qb.w*kb.w
                  + qc.x*kc.x + qc.y*kc.y + qc.z*kc.z + qc.w*kc.w
                  + qd.x*kd.x + qd.y*kd.y + qd.z*kd.z + qd.w*kd.w;
        float kss = ka.x*ka.x + ka.y*ka.y + ka.z*ka.z + ka.w*ka.w
                  + kb.x*kb.x + kb.y*kb.y + kb.z*kb.z + kb.w*kb.w
                  + kc.x*kc.x + kc.y*kc.y + kc.z*kc.z + kc.w*kc.w
                  + kd.x*kd.x + kd.y*kd.y + kd.z*kd.z + kd.w*kd.w;
        dot += __shfl_xor(dot, 1); dot += __shfl_xor(dot, 2);
        kss += __shfl_xor(kss, 1); kss += __shfl_xor(kss, 2);

        if (lane4 == 0) {
            float s = dot * fabsf(dot) / kss;        // monotone surrogate
            unsigned u = __float_as_uint(s);
            sk[row] = (u >> 31) ? ~u : (u | 0x80000000u);
        }
    }
}

__device__ __forceinline__ void reduce_hist(unsigned (*histR)[256],
                                            unsigned* hist, int t)
{
    if (t < 256) {
        unsigned h = 0;
        #pragma unroll
        for (int r = 0; r < 8; ++r) h += histR[r][t];
        hist[t] = h;
    }
    __syncthreads();
}

// inclusive suffix sum over 256 bins: scan[t] = sum_{e>=t} hist[e]
__device__ __forceinline__ void suffix_scan_256(const unsigned* hist,
                                                unsigned* scan,
                                                unsigned* wbase, int t)
{
    const int lane = t & 63, w4 = t >> 6;
    unsigned v = (t < 256) ? hist[t] : 0u;
    #pragma unroll
    for (int off = 1; off < 64; off <<= 1) {
        unsigned u2 = __shfl_down(v, off);
        if (lane + off < 64) v += u2;
    }
    if (t < 256 && lane == 0) wbase[w4] = v;
    __syncthreads();
    if (t < 256) {
        for (int w = w4 + 1; w < 4; ++w) v += wbase[w];
        scan[t] = v;
    }
    __syncthreads();
}

__global__ __launch_bounds__(1024) void topk_kernel(
    const float* __restrict__ q,
    const float* __restrict__ keys,
    const float* __restrict__ values,
    const float* __restrict__ gp,
    const unsigned* __restrict__ skeys,
    float* __restrict__ out)
{
    const int b = blockIdx.x;
    const int t = threadIdx.x;

    __shared__ unsigned   skey[LSEQ];       // 64 KB surrogate keys
    __shared__ unsigned   histR[8][256];    // 8 KB replicated histogram
    __shared__ unsigned   hist[256];
    __shared__ unsigned   scan[256];
    __shared__ unsigned   wbase[4];
    __shared__ unsigned   cidx[NCAND];      // candidate row indices
    __shared__ ulonglong2 cand[NCAND];      // {sortable fp64 key, ~idx}
    __shared__ double     wsum[4];
    __shared__ unsigned   sh_hi8, sh_k, sh_t16, ccount;

    // ---- init ----
    ((unsigned*)histR)[t]        = 0u;
    ((unsigned*)histR)[t + 1024] = 0u;
    if (t == 0) { ccount = 0u; sh_hi8 = 0u; sh_k = KPAD; sh_t16 = 0u; }
    __syncthreads();

    // ---- load keys ws -> LDS (uint4), fused pass-0 histogram ----
    const uint4* wk4 = reinterpret_cast<const uint4*>(skeys + (size_t)b * LSEQ);
    #pragma unroll
    for (int it = 0; it < 4; ++it) {
        const int i = it * 1024 + t;
        uint4 v = wk4[i];
        reinterpret_cast<uint4*>(skey)[i] = v;
        atomicAdd(&histR[t & 7][v.x >> 24], 1u);
        atomicAdd(&histR[t & 7][v.y >> 24], 1u);
        atomicAdd(&histR[t & 7][v.z >> 24], 1u);
        atomicAdd(&histR[t & 7][v.w >> 24], 1u);
    }
    __syncthreads();

    // ---- radix pass 0 (top 8 bits) ----
    reduce_hist(histR, hist, t);
    suffix_scan_256(hist, scan, wbase, t);
    if (t < 256 && scan[t] >= KPAD && (t == 255 || scan[t + 1] < KPAD)) {
        sh_hi8 = (unsigned)t;
        sh_k   = KPAD - ((t == 255) ? 0u : scan[t + 1]);
    }
    __syncthreads();

    // ---- radix pass 1 (next 8 bits, within chosen bin) ----
    ((unsigned*)histR)[t]        = 0u;
    ((unsigned*)histR)[t + 1024] = 0u;
    __syncthreads();
    const unsigned hi8  = sh_hi8;
    const unsigned kcur = sh_k;
    #pragma unroll
    for (int it = 0; it < 16; ++it) {
        unsigned key = skey[it * 1024 + t];
        if ((key >> 24) == hi8)
            atomicAdd(&histR[t & 7][(key >> 16) & 255u], 1u);
    }
    __syncthreads();
    reduce_hist(histR, hist, t);
    suffix_scan_256(hist, scan, wbase, t);
    if (t < 256 && scan[t] >= kcur && (t == 255 || scan[t + 1] < kcur))
        sh_t16 = (hi8 << 8) | (unsigned)t;
    __syncthreads();
    const unsigned T16 = sh_t16;

    // ---- compact candidates (key16 >= T16) ----
    #pragma unroll
    for (int it = 0; it < 16; ++it) {
        const int l = it * 1024 + t;
        unsigned key = skey[l];
        if ((key >> 16) >= T16) {
            unsigned pos = atomicAdd(&ccount, 1u);
            if (pos < NCAND) cidx[pos] = (unsigned)l;
        }
    }
    __syncthreads();
    const unsigned total = (ccount < (unsigned)NCAND) ? ccount : (unsigned)NCAND;

    // ---- exact fp64 sims for candidates (verified numerics) ----
    const float4* q4 = reinterpret_cast<const float4*>(q) + b * (DIM / 4);
    const float4* k4 = reinterpret_cast<const float4*>(keys)
                     + (size_t)b * LSEQ * (DIM / 4);
    const int j = t & 15;
    const float4 qv = q4[j];
    const double qx = qv.x, qy = qv.y, qz = qv.z, qw = qv.w;
    double qss = qx*qx + qy*qy + qz*qz + qw*qw;
    #pragma unroll
    for (int m = 1; m < 16; m <<= 1) qss += __shfl_xor(qss, m);
    const double scale = (double)gp[0] / sqrt(qss);

    const int cslot = t >> 4;                // 64 candidates per sweep
    for (int sweep = 0; sweep < NCAND / 64; ++sweep) {
        const int cc = sweep * 64 + cslot;
        if (cc < (int)total) {
            const int row = (int)cidx[cc];
            float4 kv = k4[row * 16 + j];
            const double kx = kv.x, ky = kv.y, kz = kv.z, kw = kv.w;
            double dot = qx*kx + qy*ky + qz*kz + qw*kw;
            double kss = kx*kx + ky*ky + kz*kz + kw*kw;
            #pragma unroll
            for (int m = 1; m < 16; m <<= 1) {
                dot += __shfl_xor(dot, m);
                kss += __shfl_xor(kss, m);
            }
            if (j == 0) {
                double sim = scale * dot / sqrt(kss);
                unsigned long long u =
                    (unsigned long long)__double_as_longlong(sim);
                unsigned long long k64 =
                    (u >> 63) ? ~u : (u | 0x8000000000000000ull);
                cand[cc] = make_ulonglong2(
                    k64, (unsigned long long)(0xFFFFFFFFu - (unsigned)row));
            }
        } else if (j == 0) {
            cand[cc] = make_ulonglong2(0ull, 0ull);   // pad = smallest
        }
    }
    __syncthreads();

    // ---- bitonic sort 512 ascending by (key, ~idx) (verified network) ----
    for (int size = 2; size <= NCAND; size <<= 1) {
        for (int stride = size >> 1; stride > 0; stride >>= 1) {
            __syncthreads();
            if (t < 256) {
                int i  = ((t & ~(stride - 1)) << 1) | (t & (stride - 1));
                int jj = i + stride;
                bool up = ((i & size) == 0);
                ulonglong2 a = cand[i], c = cand[jj];
                bool agt = (a.x > c.x) || (a.x == c.x && a.y > c.y);
                if (agt == up) { cand[i] = c; cand[jj] = a; }
            }
        }
    }
    __syncthreads();

    // ---- epilogue: softmax (fp64, verified) + values gather ----
    double e = 0.0;
    unsigned idx = 0u;
    if (t < 256) {
        ulonglong2 v = cand[511 - t];
        idx = 0xFFFFFFFFu - (unsigned)v.y;
        unsigned long long ub = (v.x & 0x8000000000000000ull)
                              ? (v.x ^ 0x8000000000000000ull) : ~v.x;
        double sv = __longlong_as_double((long long)ub);

        ulonglong2 vm = cand[511];
        unsigned long long um = (vm.x & 0x8000000000000000ull)
                              ? (vm.x ^ 0x8000000000000000ull) : ~vm.x;
        double fm = __longlong_as_double((long long)um);

        e = exp(sv - fm);
        double esum = e;
        #pragma unroll
        for (int m = 1; m < 64; m <<= 1) esum += __shfl_xor(esum, m);
        if ((t & 63) == 0) wsum[t >> 6] = esum;
    }
    __syncthreads();
    if (t < 256) {
        const double tot = wsum[0] + wsum[1] + wsum[2] + wsum[3];
        out[b * KSEL + t]                = values[(size_t)b * LSEQ + idx];
        out[BATCH * KSEL + b * KSEL + t] = (float)(e / tot);
    }
}

// ---------------------------------------------------------------------------
extern "C" void kernel_launch(void* const* d_in, const int* in_sizes, int n_in,
                              void* d_out, int out_size, void* d_ws, size_t ws_size,
                              hipStream_t stream)
{
    const float* q      = (const float*)d_in[0];  // (B,1,D)
    const float* keys   = (const float*)d_in[1];  // (B,L,D)
    const float* values = (const float*)d_in[2];  // (B,L,1)
    const float* g      = (const float*)d_in[3];  // scalar
    float* out  = (float*)d_out;                  // [B*K values_sel | B*K weights]
    unsigned* skeys = (unsigned*)d_ws;            // 4 MB surrogate keys

    sim32_kernel<<<dim3(BATCH * (LSEQ / 256)), dim3(256), 0, stream>>>(q, keys, skeys);
    topk_kernel<<<dim3(BATCH), dim3(1024), 0, stream>>>(q, keys, values, g, skeys, out);
}